// Round 6
// baseline (507.983 us; speedup 1.0000x reference)
//
#include <hip/hip_runtime.h>
#include <math.h>

namespace {

typedef float f32x2 __attribute__((ext_vector_type(2)));

constexpr int B_TOTAL = 131072;
constexpr int T_STEPS = 32;
constexpr int EPB     = 128;     // elements per block (256 threads, 2 lanes/elem)

constexpr double dG   = 9.81;
constexpr double dM   = 0.1667;
constexpr double dCAF = 5.0 * 0.25 * dM * dG;
constexpr double dCAR = dCAF;
constexpr double dLF  = 0.09 - 0.036;
constexpr double dLR  = 0.036;
constexpr double dIZ  = 0.000267;

constexpr float A33N = (float)(-(2.0 * dCAF + 2.0 * dCAR));
constexpr float A35N = (float)(-(2.0 * dCAF * dLF - 2.0 * dCAR * dLR));
constexpr float A53N = (float)(-(2.0 * dLF * dCAF - 2.0 * dLR * dCAR));
constexpr float A55N = (float)(-(2.0 * dLF * dLF * dCAF + 2.0 * dLR * dLR * dCAR));
constexpr float ST1  = (float)(2.0 * dCAF / dM);
constexpr float ST5  = (float)(2.0 * dLF * dCAF / dIZ);
constexpr float MF   = (float)dM;
constexpr float IZF  = (float)dIZ;
constexpr float R0M  = (float)(0.05 * dG / dM);
constexpr float R1M  = (float)(0.05 * dG / dM);
constexpr float R2I  = (float)(0.05 * dG * 0.2 / dIZ);
constexpr float THR_OFF = 0.24f;
constexpr float THR_RAT = 6.98f;
constexpr float DT    = 0.01f;
constexpr float PI_F  = (float)3.14159265358979323846;
constexpr float TWOPI = (float)(2.0 * 3.14159265358979323846);
constexpr float INV2PI = (float)(1.0 / (2.0 * 3.14159265358979323846));
constexpr float TWO_LOG2E = 2.8853900817779268f;   // 2*log2(e)

__device__ __forceinline__ float fast_tanh(float x) {
    x = fminf(10.0f, fmaxf(-10.0f, x));
    const float e = __builtin_amdgcn_exp2f(x * TWO_LOG2E);
    return (e - 1.0f) * __builtin_amdgcn_rcpf(e + 1.0f);
}

// packed f32: 2 exact f32 FMAs per issue slot (weights now lane-dependent -> "v")
__device__ __forceinline__ void pk_fma(f32x2& acc, f32x2 x, f32x2 w) {
    asm("v_pk_fma_f32 %0, %1, %2, %0" : "+v"(acc) : "v"(x), "v"(w));
}
__device__ __forceinline__ f32x2 pk_mul(f32x2 x, f32x2 w) {
    f32x2 r;
    asm("v_pk_mul_f32 %0, %1, %2" : "=v"(r) : "v"(x), "v"(w));
    return r;
}

// LDS swizzle: float-element e (0..31) within row r (XOR touches bits 2..4 only,
// so float4 groups stay contiguous & aligned).
__device__ __forceinline__ int swz(int row, int e) { return e ^ ((row & 7) << 2); }

__global__ __launch_bounds__(256, 4)
void rollout_kernel(const float* __restrict__ fs,     // B x 4 x 8
                    const float* __restrict__ acts,   // B x 32 x 2
                    const float* __restrict__ w1g,    // 16 x 32
                    const float* __restrict__ b1g,    // 16
                    const float* __restrict__ w2g,    // 3 x 16
                    const float* __restrict__ b2g,    // 3
                    const int*   __restrict__ en,     // 1
                    float*       __restrict__ out)    // B x 32 x 8
{
    __shared__ float sbuf[EPB * 32];   // 16 KB: init-state in / output staging

    const int tid  = threadIdx.x;
    const int h    = tid & 1;          // half: 0 -> rows 0..7, 1 -> rows 8..15
    const int elem = tid >> 1;         // element within block (0..127)
    const size_t blk_base = (size_t)blockIdx.x * EPB;

    // ---- coalesced load of the block's 128x32 init-state region ----
    {
        const float4* fsb = reinterpret_cast<const float4*>(fs + blk_base * 32);
        #pragma unroll
        for (int k = 0; k < 4; ++k) {
            const int q   = k * 256 + tid;      // float4 idx (0..1023)
            const int row = q >> 3;
            const int e   = (q & 7) << 2;
            *reinterpret_cast<float4*>(&sbuf[row * 32 + swz(row, e)]) = fsb[q];
        }
    }
    __syncthreads();

    // 4-timestep window as 16 f32 pairs, statically rotated (oldest group = t&3).
    // Both lanes of a pair hold the full window (same values, same wave).
    f32x2 wp[16];
    float s0, s1, s2, s3, s4, s5, thr, steer;
    {
        float w[32];
        #pragma unroll
        for (int i = 0; i < 8; ++i) {
            const float4 v = *reinterpret_cast<const float4*>(&sbuf[elem * 32 + swz(elem, 4 * i)]);
            w[4*i+0] = v.x; w[4*i+1] = v.y; w[4*i+2] = v.z; w[4*i+3] = v.w;
        }
        #pragma unroll
        for (int i = 0; i < 16; ++i) { wp[i].x = w[2*i]; wp[i].y = w[2*i+1]; }
        s0 = w[24]; s1 = w[25]; s2 = w[26]; s3 = w[27];
        s4 = w[28]; s5 = w[29]; thr = w[30]; steer = w[31];
    }
    // rows are pair-private in sbuf (each pair reads/writes only its own row,
    // lanes of a pair are wave-synchronous) -> no barrier needed before reuse.

    const int rnn = *en;

    // this lane's 8 layer-1 biases (lane-dependent, 8 VGPRs, loop-invariant)
    float bias1[8];
    {
        const float4 b0 = *reinterpret_cast<const float4*>(b1g + h * 8);
        const float4 b1 = *reinterpret_cast<const float4*>(b1g + h * 8 + 4);
        bias1[0]=b0.x; bias1[1]=b0.y; bias1[2]=b0.z; bias1[3]=b0.w;
        bias1[4]=b1.x; bias1[5]=b1.y; bias1[6]=b1.z; bias1[7]=b1.w;
    }
    const float bias2_0 = b2g[0], bias2_1 = b2g[1], bias2_2 = b2g[2];

    const f32x2* w1p = reinterpret_cast<const f32x2*>(w1g);  // 16 rows x 16 pairs
    const f32x2* w2p = reinterpret_cast<const f32x2*>(w2g);  // 3 rows x 8 pairs

    // opaque uniform offset: keeps per-step weight loads inside the loop
    // (no giant hoist -> no spill).
    int o1 = 0;

    for (int tc = 0; tc < T_STEPS; tc += 4) {
        // actions for 4 steps straight to registers (pair-broadcast, L1/L2-served)
        const float4* arow = reinterpret_cast<const float4*>(
            acts + (blk_base + elem) * 64 + tc * 2);
        const float4 a01 = arow[0];
        const float4 a23 = arow[1];

        #pragma unroll
        for (int tl = 0; tl < 4; ++tl) {
            asm volatile("" : "+s"(o1));

            const float ax = (tl == 0) ? a01.x : (tl == 1) ? a01.z : (tl == 2) ? a23.x : a23.z;
            const float ay = (tl == 0) ? a01.y : (tl == 1) ? a01.w : (tl == 2) ? a23.y : a23.w;

            float sn, c;
            __sincosf(s4, &sn, &c);

            const float Vx = s1 * c + s3 * sn;
            const float v3 = c * s3 - sn * s1;
            const float v5 = s5;

            const float inv_mvx  = __builtin_amdgcn_rcpf(MF * Vx);
            const float inv_izvx = __builtin_amdgcn_rcpf(IZF * Vx);
            const float a33 = A33N * inv_mvx;
            const float a35 = -Vx + A35N * inv_mvx;
            const float a53 = A53N * inv_izvx;
            const float a55 = A55N * inv_izvx;

            const float d0 = Vx;
            float       d1 = (thr - THR_OFF) * THR_RAT;
            const float d2 = v3;
            float       d3 = a33 * v3 + a35 * v5 + ST1 * steer;
            const float d4 = v5;
            float       d5 = a53 * v3 + a55 * v5 + ST5 * steer;

            if (rnn) {
                // ---- layer 1: this lane computes rows h*8 .. h*8+7 ----
                // ordered pair i: slot o=i>>2, within-slot k=i&3;
                // physical = ((tl+o)&3)*4 + k  (all compile-time).
                const f32x2* __restrict__ wrb = w1p + o1 + h * 128;
                float y1[8];
                #pragma unroll
                for (int jj = 0; jj < 8; ++jj) {
                    const f32x2* __restrict__ wr = wrb + jj * 16;
                    f32x2 acc = pk_mul(wp[(tl & 3) << 2], wr[0]);
                    #pragma unroll
                    for (int i = 1; i < 16; ++i) {
                        const int phys = (((tl + (i >> 2)) & 3) << 2) | (i & 3);
                        pk_fma(acc, wp[phys], wr[i]);
                    }
                    y1[jj] = fast_tanh(acc.x + acc.y + bias1[jj]);
                }
                f32x2 y1p[4];
                #pragma unroll
                for (int i = 0; i < 4; ++i) { y1p[i].x = y1[2*i]; y1p[i].y = y1[2*i+1]; }

                // ---- layer 2: 4-pair partial per lane, combine across the pair ----
                const f32x2* __restrict__ w2r = w2p + o1 + h * 4;
                float part0, part1, part2;
                {
                    f32x2 q0 = pk_mul(y1p[0], w2r[0]);
                    f32x2 q1 = pk_mul(y1p[0], w2r[8]);
                    f32x2 q2 = pk_mul(y1p[0], w2r[16]);
                    #pragma unroll
                    for (int i = 1; i < 4; ++i) {
                        pk_fma(q0, y1p[i], w2r[i]);
                        pk_fma(q1, y1p[i], w2r[8 + i]);
                        pk_fma(q2, y1p[i], w2r[16 + i]);
                    }
                    part0 = q0.x + q0.y;
                    part1 = q1.x + q1.y;
                    part2 = q2.x + q2.y;
                }
                const float z0 = part0 + __shfl_xor(part0, 1, 64) + bias2_0;
                const float z1 = part1 + __shfl_xor(part1, 1, 64) + bias2_1;
                const float z2 = part2 + __shfl_xor(part2, 1, 64) + bias2_2;

                d1 += fast_tanh(z0) * R0M;
                d3 += fast_tanh(z1) * R1M;
                d5 += fast_tanh(z2) * R2I;
            }

            const float ns0 = s0 + (c * d0 - sn * d2) * DT;
            const float ns1 = s1 + (c * d1 - sn * d3) * DT;
            const float ns2 = s2 + (sn * d0 + c * d2) * DT;
            const float ns3 = s3 + (sn * d1 + c * d3) * DT;
            float aa = s4 + d4 * DT + PI_F;
            aa = aa - floorf(aa * INV2PI) * TWOPI;
            const float ns4 = aa - PI_F;
            const float ns5 = s5 + d5 * DT;

            // stage this step's 8 outputs: even lane writes first float4, odd second
            {
                const float4 v = h ? make_float4(ns4, ns5, ax, ay)
                                   : make_float4(ns0, ns1, ns2, ns3);
                *reinterpret_cast<float4*>(&sbuf[elem * 32 + swz(elem, tl * 8 + h * 4)]) = v;
            }

            // overwrite oldest window slot (group tl&3) with the new timestep
            {
                const int g = (tl & 3) << 2;
                wp[g+0].x = ns0; wp[g+0].y = ns1;
                wp[g+1].x = ns2; wp[g+1].y = ns3;
                wp[g+2].x = ns4; wp[g+2].y = ns5;
                wp[g+3].x = ax;  wp[g+3].y = ay;
            }

            s0 = ns0; s1 = ns1; s2 = ns2; s3 = ns3;
            s4 = ns4; s5 = ns5; thr = ax; steer = ay;
        }

        // ---- flush 4-step chunk: full 128-B lines per 8-lane group ----
        __syncthreads();
        #pragma unroll
        for (int k = 0; k < 4; ++k) {
            const int q   = k * 256 + tid;
            const int row = q >> 3;
            const int e   = (q & 7) << 2;
            const float4 v = *reinterpret_cast<const float4*>(&sbuf[row * 32 + swz(row, e)]);
            *reinterpret_cast<float4*>(&out[(blk_base + row) * 256 + tc * 8 + e]) = v;
        }
        __syncthreads();
    }
}

} // namespace

extern "C" void kernel_launch(void* const* d_in, const int* in_sizes, int n_in,
                              void* d_out, int out_size, void* d_ws, size_t ws_size,
                              hipStream_t stream) {
    const float* fs = (const float*)d_in[0];
    const float* ac = (const float*)d_in[1];
    const float* w1 = (const float*)d_in[2];
    const float* b1 = (const float*)d_in[3];
    const float* w2 = (const float*)d_in[4];
    const float* b2 = (const float*)d_in[5];
    const int*   en = (const int*)d_in[6];
    float* out = (float*)d_out;

    dim3 grid(B_TOTAL / EPB), block(256);
    hipLaunchKernelGGL(rollout_kernel, grid, block, 0, stream,
                       fs, ac, w1, b1, w2, b2, en, out);
}

// Round 7
// 98.386 us; speedup vs baseline: 5.1632x; 5.1632x over previous
//
#include <hip/hip_runtime.h>
#include <math.h>

namespace {

typedef float f32x2 __attribute__((ext_vector_type(2)));

constexpr int B_TOTAL = 131072;
constexpr int T_STEPS = 32;
constexpr int EPB     = 128;     // elements per block; 256 thr = 4 waves, wave-pair per 64 elems

constexpr double dG   = 9.81;
constexpr double dM   = 0.1667;
constexpr double dCAF = 5.0 * 0.25 * dM * dG;
constexpr double dCAR = dCAF;
constexpr double dLF  = 0.09 - 0.036;
constexpr double dLR  = 0.036;
constexpr double dIZ  = 0.000267;

constexpr float A33N = (float)(-(2.0 * dCAF + 2.0 * dCAR));
constexpr float A35N = (float)(-(2.0 * dCAF * dLF - 2.0 * dCAR * dLR));
constexpr float A53N = (float)(-(2.0 * dLF * dCAF - 2.0 * dLR * dCAR));
constexpr float A55N = (float)(-(2.0 * dLF * dLF * dCAF + 2.0 * dLR * dLR * dCAR));
constexpr float ST1  = (float)(2.0 * dCAF / dM);
constexpr float ST5  = (float)(2.0 * dLF * dCAF / dIZ);
constexpr float MF   = (float)dM;
constexpr float IZF  = (float)dIZ;
constexpr float R0M  = (float)(0.05 * dG / dM);
constexpr float R1M  = (float)(0.05 * dG / dM);
constexpr float R2I  = (float)(0.05 * dG * 0.2 / dIZ);
constexpr float THR_OFF = 0.24f;
constexpr float THR_RAT = 6.98f;
constexpr float DT    = 0.01f;
constexpr float PI_F  = (float)3.14159265358979323846;
constexpr float TWOPI = (float)(2.0 * 3.14159265358979323846);
constexpr float INV2PI = (float)(1.0 / (2.0 * 3.14159265358979323846));
constexpr float TWO_LOG2E = 2.8853900817779268f;   // 2*log2(e)

__device__ __forceinline__ float fast_tanh(float x) {
    x = fminf(10.0f, fmaxf(-10.0f, x));
    const float e = __builtin_amdgcn_exp2f(x * TWO_LOG2E);
    return (e - 1.0f) * __builtin_amdgcn_rcpf(e + 1.0f);
}

// packed f32: 2 exact f32 FMAs per issue slot; weight operand wave-uniform -> SGPR pair.
__device__ __forceinline__ void pk_fma(f32x2& acc, f32x2 x, f32x2 w) {
    asm("v_pk_fma_f32 %0, %1, %2, %0" : "+v"(acc) : "v"(x), "s"(w));
}
__device__ __forceinline__ f32x2 pk_mul(f32x2 x, f32x2 w) {
    f32x2 r;
    asm("v_pk_mul_f32 %0, %1, %2" : "=v"(r) : "v"(x), "s"(w));
    return r;
}

// LDS swizzle: float-element e (0..31) within row r (XOR touches bits 2..4 only).
__device__ __forceinline__ int swz(int row, int e) { return e ^ ((row & 7) << 2); }

__global__ __launch_bounds__(256, 4)
void rollout_kernel(const float* __restrict__ fs,     // B x 4 x 8
                    const float* __restrict__ acts,   // B x 32 x 2
                    const float* __restrict__ w1g,    // 16 x 32
                    const float* __restrict__ b1g,    // 16
                    const float* __restrict__ w2g,    // 3 x 16
                    const float* __restrict__ b2g,    // 3
                    const int*   __restrict__ en,     // 1
                    float*       __restrict__ out)    // B x 32 x 8
{
    __shared__ float sbuf[EPB * 32];          // 16 KB: init-state / output staging
    __shared__ float abuf[EPB * 32];          // 16 KB: actions, 16 steps
    __shared__ float xbuf[2][2][3][64];       //  6 KB: layer-2 partial exchange [pair][h][comp][lane]

    const int tid = threadIdx.x;
    const int wv  = tid >> 6;                 // wave id 0..3
    const int l   = tid & 63;
    const int pr  = wv >> 1;                  // wave-pair 0/1
    const int h   = wv & 1;                   // row-half: 0 -> rows 0..7, 1 -> rows 8..15
    // wave-uniform copy the compiler can prove uniform -> keeps weight loads SCALAR
    const int hu  = __builtin_amdgcn_readfirstlane(h);
    const int elem = pr * 64 + l;             // element within block (0..127)
    const size_t blk_base = (size_t)blockIdx.x * EPB;

    // ---- coalesced load of the block's 128x32 init-state region ----
    {
        const float4* fsb = reinterpret_cast<const float4*>(fs + blk_base * 32);
        #pragma unroll
        for (int k = 0; k < 4; ++k) {
            const int q   = k * 256 + tid;
            const int row = q >> 3;
            const int e   = (q & 7) << 2;
            *reinterpret_cast<float4*>(&sbuf[row * 32 + swz(row, e)]) = fsb[q];
        }
    }
    __syncthreads();

    // 4-timestep window as 16 f32 pairs, statically rotated (oldest group = t&3).
    // Both waves of a pair hold the full window for their shared elements.
    f32x2 wp[16];
    float s0, s1, s2, s3, s4, s5, thr, steer;
    {
        float w[32];
        #pragma unroll
        for (int i = 0; i < 8; ++i) {
            const float4 v = *reinterpret_cast<const float4*>(&sbuf[elem * 32 + swz(elem, 4 * i)]);
            w[4*i+0] = v.x; w[4*i+1] = v.y; w[4*i+2] = v.z; w[4*i+3] = v.w;
        }
        #pragma unroll
        for (int i = 0; i < 16; ++i) { wp[i].x = w[2*i]; wp[i].y = w[2*i+1]; }
        s0 = w[24]; s1 = w[25]; s2 = w[26]; s3 = w[27];
        s4 = w[28]; s5 = w[29]; thr = w[30]; steer = w[31];
    }
    // partner waves share sbuf rows -> barrier before first staging overwrite
    __syncthreads();

    const int rnn = *en;

    // this wave's 8 layer-1 biases (uniform address via hu -> scalar loads)
    float bias1[8];
    #pragma unroll
    for (int j = 0; j < 8; ++j) bias1[j] = b1g[hu * 8 + j];
    const float bias2_0 = b2g[0], bias2_1 = b2g[1], bias2_2 = b2g[2];

    const f32x2* w1p = reinterpret_cast<const f32x2*>(w1g);  // 16 rows x 16 pairs
    const f32x2* w2p = reinterpret_cast<const f32x2*>(w2g);  // 3 rows x 8 pairs

    // opaque uniform offset: keeps per-step weight loads inside the loop.
    int o1 = 0;

    for (int tc = 0; tc < T_STEPS; tc += 4) {
        if ((tc & 15) == 0) {
            // ---- coalesced action staging: 16 steps = 128 B/row ----
            __syncthreads();
            #pragma unroll
            for (int k = 0; k < 4; ++k) {
                const int q   = k * 256 + tid;
                const int row = q >> 3;
                const int e   = (q & 7) << 2;
                const float4 v = *reinterpret_cast<const float4*>(
                    &acts[(blk_base + row) * 64 + tc * 2 + e]);
                *reinterpret_cast<float4*>(&abuf[row * 32 + swz(row, e)]) = v;
            }
            __syncthreads();
        }

        #pragma unroll
        for (int tl = 0; tl < 4; ++tl) {
            const int t = tc + tl;
            asm volatile("" : "+s"(o1));

            float sn, c;
            __sincosf(s4, &sn, &c);

            const float Vx = s1 * c + s3 * sn;
            const float v3 = c * s3 - sn * s1;
            const float v5 = s5;

            const float inv_mvx  = __builtin_amdgcn_rcpf(MF * Vx);
            const float inv_izvx = __builtin_amdgcn_rcpf(IZF * Vx);
            const float a33 = A33N * inv_mvx;
            const float a35 = -Vx + A35N * inv_mvx;
            const float a53 = A53N * inv_izvx;
            const float a55 = A55N * inv_izvx;

            const float d0 = Vx;
            float       d1 = (thr - THR_OFF) * THR_RAT;
            const float d2 = v3;
            float       d3 = a33 * v3 + a35 * v5 + ST1 * steer;
            const float d4 = v5;
            float       d5 = a53 * v3 + a55 * v5 + ST5 * steer;

            const float2 act = *reinterpret_cast<const float2*>(
                &abuf[elem * 32 + swz(elem, 2 * (t & 15))]);

            if (rnn) {
                // ---- layer 1: this WAVE computes rows hu*8 .. hu*8+7 (weights scalar) ----
                const f32x2* __restrict__ wrb = w1p + o1 + hu * 128;
                float y1[8];
                #pragma unroll
                for (int jj = 0; jj < 8; ++jj) {
                    const f32x2* __restrict__ wr = wrb + jj * 16;
                    f32x2 acc = pk_mul(wp[(tl & 3) << 2], wr[0]);
                    #pragma unroll
                    for (int i = 1; i < 16; ++i) {
                        const int phys = (((tl + (i >> 2)) & 3) << 2) | (i & 3);
                        pk_fma(acc, wp[phys], wr[i]);
                    }
                    y1[jj] = fast_tanh(acc.x + acc.y + bias1[jj]);
                }
                f32x2 y1p[4];
                #pragma unroll
                for (int i = 0; i < 4; ++i) { y1p[i].x = y1[2*i]; y1p[i].y = y1[2*i+1]; }

                // ---- layer 2: 4-pair partial per wave, exchange across wave pair ----
                const f32x2* __restrict__ w2r = w2p + o1 + hu * 4;
                f32x2 q0 = pk_mul(y1p[0], w2r[0]);
                f32x2 q1 = pk_mul(y1p[0], w2r[8]);
                f32x2 q2 = pk_mul(y1p[0], w2r[16]);
                #pragma unroll
                for (int i = 1; i < 4; ++i) {
                    pk_fma(q0, y1p[i], w2r[i]);
                    pk_fma(q1, y1p[i], w2r[8 + i]);
                    pk_fma(q2, y1p[i], w2r[16 + i]);
                }
                const float part0 = q0.x + q0.y;
                const float part1 = q1.x + q1.y;
                const float part2 = q2.x + q2.y;

                xbuf[pr][h][0][l] = part0;
                xbuf[pr][h][1][l] = part1;
                xbuf[pr][h][2][l] = part2;
                __syncthreads();
                const float z0 = part0 + xbuf[pr][h ^ 1][0][l] + bias2_0;
                const float z1 = part1 + xbuf[pr][h ^ 1][1][l] + bias2_1;
                const float z2 = part2 + xbuf[pr][h ^ 1][2][l] + bias2_2;
                __syncthreads();   // protect xbuf from next step's overwrite

                d1 += fast_tanh(z0) * R0M;
                d3 += fast_tanh(z1) * R1M;
                d5 += fast_tanh(z2) * R2I;
            }

            const float ns0 = s0 + (c * d0 - sn * d2) * DT;
            const float ns1 = s1 + (c * d1 - sn * d3) * DT;
            const float ns2 = s2 + (sn * d0 + c * d2) * DT;
            const float ns3 = s3 + (sn * d1 + c * d3) * DT;
            float aa = s4 + d4 * DT + PI_F;
            aa = aa - floorf(aa * INV2PI) * TWOPI;
            const float ns4 = aa - PI_F;
            const float ns5 = s5 + d5 * DT;

            // stage this step's 8 outputs: h=0 wave writes lo float4, h=1 hi
            {
                const float4 v = h ? make_float4(ns4, ns5, act.x, act.y)
                                   : make_float4(ns0, ns1, ns2, ns3);
                *reinterpret_cast<float4*>(&sbuf[elem * 32 + swz(elem, tl * 8 + h * 4)]) = v;
            }

            // overwrite oldest window slot (group tl&3) with the new timestep
            {
                const int g = (tl & 3) << 2;
                wp[g+0].x = ns0;  wp[g+0].y = ns1;
                wp[g+1].x = ns2;  wp[g+1].y = ns3;
                wp[g+2].x = ns4;  wp[g+2].y = ns5;
                wp[g+3].x = act.x; wp[g+3].y = act.y;
            }

            s0 = ns0; s1 = ns1; s2 = ns2; s3 = ns3;
            s4 = ns4; s5 = ns5; thr = act.x; steer = act.y;
        }

        // ---- flush 4-step chunk: full 128-B lines per 8-lane group ----
        __syncthreads();
        #pragma unroll
        for (int k = 0; k < 4; ++k) {
            const int q   = k * 256 + tid;
            const int row = q >> 3;
            const int e   = (q & 7) << 2;
            const float4 v = *reinterpret_cast<const float4*>(&sbuf[row * 32 + swz(row, e)]);
            *reinterpret_cast<float4*>(&out[(blk_base + row) * 256 + tc * 8 + e]) = v;
        }
        __syncthreads();
    }
}

} // namespace

extern "C" void kernel_launch(void* const* d_in, const int* in_sizes, int n_in,
                              void* d_out, int out_size, void* d_ws, size_t ws_size,
                              hipStream_t stream) {
    const float* fs = (const float*)d_in[0];
    const float* ac = (const float*)d_in[1];
    const float* w1 = (const float*)d_in[2];
    const float* b1 = (const float*)d_in[3];
    const float* w2 = (const float*)d_in[4];
    const float* b2 = (const float*)d_in[5];
    const int*   en = (const int*)d_in[6];
    float* out = (float*)d_out;

    dim3 grid(B_TOTAL / EPB), block(256);
    hipLaunchKernelGGL(rollout_kernel, grid, block, 0, stream,
                       fs, ac, w1, b1, w2, b2, en, out);
}

// Round 8
// 95.705 us; speedup vs baseline: 5.3078x; 1.0280x over previous
//
#include <hip/hip_runtime.h>
#include <math.h>

namespace {

typedef float f32x2 __attribute__((ext_vector_type(2)));

constexpr int B_TOTAL = 131072;
constexpr int T_STEPS = 32;
constexpr int EPB     = 64;      // elements per block; 128 thr = 2 waves share 64 elems

constexpr double dG   = 9.81;
constexpr double dM   = 0.1667;
constexpr double dCAF = 5.0 * 0.25 * dM * dG;
constexpr double dCAR = dCAF;
constexpr double dLF  = 0.09 - 0.036;
constexpr double dLR  = 0.036;
constexpr double dIZ  = 0.000267;

constexpr float A33N = (float)(-(2.0 * dCAF + 2.0 * dCAR));
constexpr float A35N = (float)(-(2.0 * dCAF * dLF - 2.0 * dCAR * dLR));
constexpr float A53N = (float)(-(2.0 * dLF * dCAF - 2.0 * dLR * dCAR));
constexpr float A55N = (float)(-(2.0 * dLF * dLF * dCAF + 2.0 * dLR * dLR * dCAR));
constexpr float ST1  = (float)(2.0 * dCAF / dM);
constexpr float ST5  = (float)(2.0 * dLF * dCAF / dIZ);
constexpr float MF   = (float)dM;
constexpr float IZF  = (float)dIZ;
constexpr float R0M  = (float)(0.05 * dG / dM);
constexpr float R1M  = (float)(0.05 * dG / dM);
constexpr float R2I  = (float)(0.05 * dG * 0.2 / dIZ);
constexpr float THR_OFF = 0.24f;
constexpr float THR_RAT = 6.98f;
constexpr float DT    = 0.01f;
constexpr float PI_F  = (float)3.14159265358979323846;
constexpr float TWOPI = (float)(2.0 * 3.14159265358979323846);
constexpr float INV2PI = (float)(1.0 / (2.0 * 3.14159265358979323846));
constexpr float TWO_LOG2E = 2.8853900817779268f;   // 2*log2(e)

// tanh(x) = 1 - 2/(e+1), e = 2^(x*2*log2e).  No clamps needed:
// x->+inf: e=inf, rcp=0, t=1.  x->-inf: e=0, rcp(1)=1, t=-1.
__device__ __forceinline__ float fast_tanh(float x) {
    const float e = __builtin_amdgcn_exp2f(x * TWO_LOG2E);
    return fmaf(-2.0f, __builtin_amdgcn_rcpf(e + 1.0f), 1.0f);
}

// packed f32: 2 exact f32 FMAs per issue slot; weight operand wave-uniform -> SGPR pair.
__device__ __forceinline__ void pk_fma(f32x2& acc, f32x2 x, f32x2 w) {
    asm("v_pk_fma_f32 %0, %1, %2, %0" : "+v"(acc) : "v"(x), "s"(w));
}

// LDS swizzle: float-element e (0..31) within row r (XOR touches bits 2..4 only).
__device__ __forceinline__ int swz(int row, int e) { return e ^ ((row & 7) << 2); }

__global__ __launch_bounds__(128, 4)
void rollout_kernel(const float* __restrict__ fs,     // B x 4 x 8
                    const float* __restrict__ acts,   // B x 32 x 2
                    const float* __restrict__ w1g,    // 16 x 32
                    const float* __restrict__ b1g,    // 16
                    const float* __restrict__ w2g,    // 3 x 16
                    const float* __restrict__ b2g,    // 3
                    const int*   __restrict__ en,     // 1
                    float*       __restrict__ out)    // B x 32 x 8
{
    __shared__ float sbuf[EPB * 32];          // 8 KB: init-state / output staging
    __shared__ float abuf[EPB * 32];          // 8 KB: actions, 16 steps
    __shared__ float xbuf[2][2][3][64];       // 3 KB: [parity][h][comp][lane]

    const int tid = threadIdx.x;
    const int h   = tid >> 6;                 // wave 0 -> rows 0..7, wave 1 -> rows 8..15
    const int hu  = __builtin_amdgcn_readfirstlane(h);  // provably wave-uniform
    const int l   = tid & 63;                 // element within block
    const size_t blk_base = (size_t)blockIdx.x * EPB;

    // ---- coalesced load of the block's 64x32 init-state region ----
    {
        const float4* fsb = reinterpret_cast<const float4*>(fs + blk_base * 32);
        #pragma unroll
        for (int k = 0; k < 4; ++k) {
            const int q   = k * 128 + tid;
            const int row = q >> 3;
            const int e   = (q & 7) << 2;
            *reinterpret_cast<float4*>(&sbuf[row * 32 + swz(row, e)]) = fsb[q];
        }
    }
    __syncthreads();

    // 4-timestep window as 16 f32 pairs, statically rotated (oldest group = t&3).
    f32x2 wp[16];
    float s0, s1, s2, s3, s4, s5, thr, steer;
    {
        float w[32];
        #pragma unroll
        for (int i = 0; i < 8; ++i) {
            const float4 v = *reinterpret_cast<const float4*>(&sbuf[l * 32 + swz(l, 4 * i)]);
            w[4*i+0] = v.x; w[4*i+1] = v.y; w[4*i+2] = v.z; w[4*i+3] = v.w;
        }
        #pragma unroll
        for (int i = 0; i < 16; ++i) { wp[i].x = w[2*i]; wp[i].y = w[2*i+1]; }
        s0 = w[24]; s1 = w[25]; s2 = w[26]; s3 = w[27];
        s4 = w[28]; s5 = w[29]; thr = w[30]; steer = w[31];
    }
    __syncthreads();   // partner wave must finish reading before staging overwrites

    const int rnn = *en;

    // biases folded into accumulator inits (pairs {b,0}); layer-2 bias only on h=0
    f32x2 bp1[8];
    #pragma unroll
    for (int j = 0; j < 8; ++j) { bp1[j].x = b1g[hu * 8 + j]; bp1[j].y = 0.0f; }
    f32x2 bp2[3];
    #pragma unroll
    for (int c3 = 0; c3 < 3; ++c3) { bp2[c3].x = hu ? 0.0f : b2g[c3]; bp2[c3].y = 0.0f; }

    const f32x2* w1p = reinterpret_cast<const f32x2*>(w1g);  // 16 rows x 16 pairs
    const f32x2* w2p = reinterpret_cast<const f32x2*>(w2g);  // 3 rows x 8 pairs

    // opaque uniform offset: keeps per-step weight loads inside the loop.
    int o1 = 0;

    for (int tc = 0; tc < T_STEPS; tc += 4) {
        if ((tc & 15) == 0) {
            // ---- coalesced action staging: 16 steps = 128 B/row ----
            // (prior flush barrier / init barrier already ordered abuf reuse)
            #pragma unroll
            for (int k = 0; k < 4; ++k) {
                const int q   = k * 128 + tid;
                const int row = q >> 3;
                const int e   = (q & 7) << 2;
                const float4 v = *reinterpret_cast<const float4*>(
                    &acts[(blk_base + row) * 64 + tc * 2 + e]);
                *reinterpret_cast<float4*>(&abuf[row * 32 + swz(row, e)]) = v;
            }
            __syncthreads();
        }

        #pragma unroll
        for (int tl = 0; tl < 4; ++tl) {
            const int t = tc + tl;
            asm volatile("" : "+s"(o1));

            float sn, c;
            __sincosf(s4, &sn, &c);

            const float Vx = s1 * c + s3 * sn;
            const float v3 = c * s3 - sn * s1;
            const float v5 = s5;

            const float inv_mvx  = __builtin_amdgcn_rcpf(MF * Vx);
            const float inv_izvx = __builtin_amdgcn_rcpf(IZF * Vx);
            const float a33 = A33N * inv_mvx;
            const float a35 = -Vx + A35N * inv_mvx;
            const float a53 = A53N * inv_izvx;
            const float a55 = A55N * inv_izvx;

            const float d0 = Vx;
            float       d1 = (thr - THR_OFF) * THR_RAT;
            const float d2 = v3;
            float       d3 = a33 * v3 + a35 * v5 + ST1 * steer;
            const float d4 = v5;
            float       d5 = a53 * v3 + a55 * v5 + ST5 * steer;

            const float2 act = *reinterpret_cast<const float2*>(
                &abuf[l * 32 + swz(l, 2 * (t & 15))]);

            if (rnn) {
                // ---- layer 1: this WAVE computes rows hu*8 .. hu*8+7 (weights scalar) ----
                const f32x2* __restrict__ wrb = w1p + o1 + hu * 128;
                float y1[8];
                #pragma unroll
                for (int jj = 0; jj < 8; ++jj) {
                    const f32x2* __restrict__ wr = wrb + jj * 16;
                    f32x2 acc = bp1[jj];
                    #pragma unroll
                    for (int i = 0; i < 16; ++i) {
                        const int phys = (((tl + (i >> 2)) & 3) << 2) | (i & 3);
                        pk_fma(acc, wp[phys], wr[i]);
                    }
                    y1[jj] = fast_tanh(acc.x + acc.y);
                }
                f32x2 y1p[4];
                #pragma unroll
                for (int i = 0; i < 4; ++i) { y1p[i].x = y1[2*i]; y1p[i].y = y1[2*i+1]; }

                // ---- layer 2: 4-pair partial per wave, exchange across the pair ----
                const f32x2* __restrict__ w2r = w2p + o1 + hu * 4;
                f32x2 q0 = bp2[0], q1 = bp2[1], q2 = bp2[2];
                #pragma unroll
                for (int i = 0; i < 4; ++i) {
                    pk_fma(q0, y1p[i], w2r[i]);
                    pk_fma(q1, y1p[i], w2r[8 + i]);
                    pk_fma(q2, y1p[i], w2r[16 + i]);
                }
                const float part0 = q0.x + q0.y;
                const float part1 = q1.x + q1.y;
                const float part2 = q2.x + q2.y;

                const int p = tl & 1;          // parity double-buffer -> 1 barrier/step
                xbuf[p][h][0][l] = part0;
                xbuf[p][h][1][l] = part1;
                xbuf[p][h][2][l] = part2;
                __syncthreads();
                const float z0 = part0 + xbuf[p][h ^ 1][0][l];
                const float z1 = part1 + xbuf[p][h ^ 1][1][l];
                const float z2 = part2 + xbuf[p][h ^ 1][2][l];

                d1 += fast_tanh(z0) * R0M;
                d3 += fast_tanh(z1) * R1M;
                d5 += fast_tanh(z2) * R2I;
            }

            const float ns0 = s0 + (c * d0 - sn * d2) * DT;
            const float ns1 = s1 + (c * d1 - sn * d3) * DT;
            const float ns2 = s2 + (sn * d0 + c * d2) * DT;
            const float ns3 = s3 + (sn * d1 + c * d3) * DT;
            float aa = s4 + d4 * DT + PI_F;
            aa = aa - floorf(aa * INV2PI) * TWOPI;
            const float ns4 = aa - PI_F;
            const float ns5 = s5 + d5 * DT;

            // stage this step's 8 outputs: h=0 wave writes lo float4, h=1 hi
            {
                const float4 v = h ? make_float4(ns4, ns5, act.x, act.y)
                                   : make_float4(ns0, ns1, ns2, ns3);
                *reinterpret_cast<float4*>(&sbuf[l * 32 + swz(l, tl * 8 + h * 4)]) = v;
            }

            // overwrite oldest window slot (group tl&3) with the new timestep
            {
                const int g = (tl & 3) << 2;
                wp[g+0].x = ns0;  wp[g+0].y = ns1;
                wp[g+1].x = ns2;  wp[g+1].y = ns3;
                wp[g+2].x = ns4;  wp[g+2].y = ns5;
                wp[g+3].x = act.x; wp[g+3].y = act.y;
            }

            s0 = ns0; s1 = ns1; s2 = ns2; s3 = ns3;
            s4 = ns4; s5 = ns5; thr = act.x; steer = act.y;
        }

        // ---- flush 4-step chunk: full 128-B lines per 8-lane group ----
        __syncthreads();
        #pragma unroll
        for (int k = 0; k < 4; ++k) {
            const int q   = k * 128 + tid;
            const int row = q >> 3;
            const int e   = (q & 7) << 2;
            const float4 v = *reinterpret_cast<const float4*>(&sbuf[row * 32 + swz(row, e)]);
            *reinterpret_cast<float4*>(&out[(blk_base + row) * 256 + tc * 8 + e]) = v;
        }
        __syncthreads();
    }
}

} // namespace

extern "C" void kernel_launch(void* const* d_in, const int* in_sizes, int n_in,
                              void* d_out, int out_size, void* d_ws, size_t ws_size,
                              hipStream_t stream) {
    const float* fs = (const float*)d_in[0];
    const float* ac = (const float*)d_in[1];
    const float* w1 = (const float*)d_in[2];
    const float* b1 = (const float*)d_in[3];
    const float* w2 = (const float*)d_in[4];
    const float* b2 = (const float*)d_in[5];
    const int*   en = (const int*)d_in[6];
    float* out = (float*)d_out;

    dim3 grid(B_TOTAL / EPB), block(128);
    hipLaunchKernelGGL(rollout_kernel, grid, block, 0, stream,
                       fs, ac, w1, b1, w2, b2, en, out);
}